// Round 1
// baseline (557.699 us; speedup 1.0000x reference)
//
#include <hip/hip_runtime.h>

// Problem constants
#define BB 256
#define TT 512
#define DIN 128
#define HH 256
#define DOUT 64
// d_out layout: x [256,513,64] then h [256,513,256]
#define XROWS ((long)BB * 513)
#define X_ELEMS ((long)BB * 513 * DOUT)

typedef short bf16x8 __attribute__((ext_vector_type(8)));
typedef float f32x4 __attribute__((ext_vector_type(4)));
typedef _Float16 half2_t __attribute__((ext_vector_type(2)));
typedef _Float16 half8_t __attribute__((ext_vector_type(8)));

static __device__ inline short f2bf(float f) {
    // round-to-nearest-even fp32 -> bf16 (no NaN handling needed here)
    unsigned u = __float_as_uint(f);
    unsigned r = (u + 0x7FFFu + ((u >> 16) & 1u)) >> 16;
    return (short)r;
}

static __device__ inline float fdot2f(half2_t a, half2_t b, float c) {
#if __has_builtin(__builtin_amdgcn_fdot2)
    return __builtin_amdgcn_fdot2(a, b, c, false);
#else
    return c + (float)a[0] * (float)b[0] + (float)a[1] * (float)b[1];
#endif
}

// ---------------------------------------------------------------------------
// Kernel A: U[b,t,:] = b_ih + inputs[b,t,:] @ W_u^T   (W_u = W_ih[:, 0:128])
// Stored into the h-section of d_out at row (b*513 + t + 1) — consumed (and
// then overwritten with h) by rnn_seq.
// GEMM: M=131072 (rows=(b,t)), K=128, N=256. bf16 MFMA 16x16x32.
// grid (2048, 4), block 256 (4 waves). Tile M64 x N64, K-chunks of 32.
// ---------------------------------------------------------------------------
__global__ __launch_bounds__(256) void gemm_u(
        const float* __restrict__ inp, const float* __restrict__ W_ih,
        const float* __restrict__ b_ih, float* __restrict__ out_h) {
    // LDS tiles, row stride 40 bf16 (80 B) to keep b128 alignment + kill conflicts
    __shared__ __align__(16) short lA[64 * 40];
    __shared__ __align__(16) short lB[64 * 40];
    const int tid = threadIdx.x;
    const int wave = tid >> 6, lane = tid & 63;
    const int quad = lane >> 4, l16 = lane & 15;
    const int m0 = blockIdx.x * 64;
    const int n0 = blockIdx.y * 64;
    // staging roles
    const int sm = tid >> 2, skg = tid & 3;   // A: row, k-group(8 floats)
    const int sn = tid & 63, bkg = tid >> 6;  // B: n-row, k-group(8 floats)

    f32x4 acc[4];
#pragma unroll
    for (int i = 0; i < 4; i++) acc[i] = (f32x4){0.f, 0.f, 0.f, 0.f};

#pragma unroll
    for (int k0 = 0; k0 < DIN; k0 += 32) {
        const float4* ap = (const float4*)(inp + (long)(m0 + sm) * DIN + k0 + skg * 8);
        float4 a0 = ap[0], a1 = ap[1];
        const float4* bp = (const float4*)(W_ih + (long)(n0 + sn) * 384 + k0 + bkg * 8);
        float4 b0 = bp[0], b1 = bp[1];
        __syncthreads();  // previous iteration's frag reads done
        bf16x8 av, bv;
        av[0] = f2bf(a0.x); av[1] = f2bf(a0.y); av[2] = f2bf(a0.z); av[3] = f2bf(a0.w);
        av[4] = f2bf(a1.x); av[5] = f2bf(a1.y); av[6] = f2bf(a1.z); av[7] = f2bf(a1.w);
        bv[0] = f2bf(b0.x); bv[1] = f2bf(b0.y); bv[2] = f2bf(b0.z); bv[3] = f2bf(b0.w);
        bv[4] = f2bf(b1.x); bv[5] = f2bf(b1.y); bv[6] = f2bf(b1.z); bv[7] = f2bf(b1.w);
        *(bf16x8*)&lA[sm * 40 + skg * 8] = av;
        *(bf16x8*)&lB[sn * 40 + bkg * 8] = bv;
        __syncthreads();
        bf16x8 af = *(const bf16x8*)&lA[(wave * 16 + l16) * 40 + quad * 8];
#pragma unroll
        for (int nt = 0; nt < 4; nt++) {
            bf16x8 bf = *(const bf16x8*)&lB[(nt * 16 + l16) * 40 + quad * 8];
            acc[nt] = __builtin_amdgcn_mfma_f32_16x16x32_bf16(af, bf, acc[nt], 0, 0, 0);
        }
    }
    // epilogue: C row = quad*4 + r, col = nt*16 + l16 ; add bias, store fp32
#pragma unroll
    for (int nt = 0; nt < 4; nt++) {
#pragma unroll
        for (int r = 0; r < 4; r++) {
            int m = m0 + wave * 16 + quad * 4 + r;       // global (b,t) row
            int col = n0 + nt * 16 + l16;
            long orow = (long)(m >> 9) * 513 + (m & 511) + 1;
            out_h[orow * HH + col] = acc[nt][r] + b_ih[col];
        }
    }
}

// ---------------------------------------------------------------------------
// Kernel B: sequential recurrence. One block (512 thr = 8 waves) per batch b.
// W_h = W_ih[:, 128:384] held in registers as fp16 pairs (64 half2 / thread).
// wave w: j-group = w&3 (j = 64*(w&3)+lane), k-half = w>>2 (k in [128*(w>>2), +128)).
// h in LDS (fp16), broadcast-read; v_dot2_f32_f16 accumulate in fp32.
// Reads U from out_h row t+1, overwrites same row with h_{t+1}.
// ---------------------------------------------------------------------------
__global__ __launch_bounds__(512) void rnn_seq(
        const float* __restrict__ x0, const float* __restrict__ h0,
        const float* __restrict__ W_ih,
        float* __restrict__ out_x, float* __restrict__ out_h) {
    __shared__ __align__(16) _Float16 hsh[HH];
    __shared__ float part[HH];
    const int b = blockIdx.x;
    const int tid = threadIdx.x;
    const int wave = tid >> 6, lane = tid & 63;
    const int jg = wave & 3, kh = wave >> 2;
    const int j = jg * 64 + lane;
    const int kbase = kh * 128;

    // load weight slice: W_ih[j, 128 + kbase .. +128) as 64 packed half2
    half2_t w[64];
    const float* wr = W_ih + (long)j * 384 + 128 + kbase;
#pragma unroll
    for (int i = 0; i < 32; i++) {
        float4 v = *(const float4*)(wr + 4 * i);
        w[2 * i]     = (half2_t){(_Float16)v.x, (_Float16)v.y};
        w[2 * i + 1] = (half2_t){(_Float16)v.z, (_Float16)v.w};
    }

    float* hrow = out_h + (long)b * 513 * HH;
    // prologue: h0 -> LDS + out row 0 ; x0 -> x row 0 ; preload c for t=0 (U row 1)
    if (tid < HH) {
        float hv = h0[(long)b * HH + tid];
        hsh[tid] = (_Float16)hv;
        hrow[tid] = hv;
    }
    if (tid < DOUT) out_x[(long)b * 513 * DOUT + tid] = x0[(long)b * DOUT + tid];
    float c = 0.f;
    if (tid < HH) c = hrow[HH + tid];
    __syncthreads();

    for (int t = 0; t < TT; t++) {
        float a0 = 0.f, a1 = 0.f, a2 = 0.f, a3 = 0.f;
#pragma unroll
        for (int i = 0; i < 16; i++) {
            half8_t hv = *(const half8_t*)&hsh[kbase + 8 * i];  // broadcast b128
            a0 = fdot2f((half2_t){hv[0], hv[1]}, w[4 * i + 0], a0);
            a1 = fdot2f((half2_t){hv[2], hv[3]}, w[4 * i + 1], a1);
            a2 = fdot2f((half2_t){hv[4], hv[5]}, w[4 * i + 2], a2);
            a3 = fdot2f((half2_t){hv[6], hv[7]}, w[4 * i + 3], a3);
        }
        float s = (a0 + a1) + (a2 + a3);
        if (wave >= 4) part[j] = s;
        __syncthreads();
        if (wave < 4) {
            float tot = s + part[j] + c;                 // c already includes b_ih
            float hn = tot >= 0.f ? tot : 0.01f * tot;   // LeakyReLU(0.01)
            hsh[j] = (_Float16)hn;
            hrow[(long)(t + 1) * HH + j] = hn;           // overwrites consumed U row
            if (t < TT - 1) c = hrow[(long)(t + 2) * HH + j];  // prefetch next U
        }
        __syncthreads();
    }
}

// ---------------------------------------------------------------------------
// Kernel C: x[b,t,:] = h[b,t,:] @ W_ho^T + b_ho for t=1..512.
// GEMM: M=131072 rows (within-b contiguous in out_h), K=256, N=64.
// grid (2048), block 256. Tile M64 x N64, K-chunks of 32.
// ---------------------------------------------------------------------------
__global__ __launch_bounds__(256) void gemm_x(
        const float* __restrict__ out_h, const float* __restrict__ W_ho,
        const float* __restrict__ b_ho, float* __restrict__ out_x) {
    __shared__ __align__(16) short lA[64 * 40];
    __shared__ __align__(16) short lB[64 * 40];
    const int tid = threadIdx.x;
    const int wave = tid >> 6, lane = tid & 63;
    const int quad = lane >> 4, l16 = lane & 15;
    const int m0 = blockIdx.x * 64;
    const int bb = m0 >> 9, t0 = m0 & 511;   // 64-row tile never straddles b
    const float* hsrc = out_h + ((long)bb * 513 + 1 + t0) * HH;
    float* xdst = out_x + ((long)bb * 513 + 1 + t0) * DOUT;
    const int sm = tid >> 2, skg = tid & 3;
    const int sn = tid & 63, bkg = tid >> 6;

    f32x4 acc[4];
#pragma unroll
    for (int i = 0; i < 4; i++) acc[i] = (f32x4){0.f, 0.f, 0.f, 0.f};

#pragma unroll
    for (int k0 = 0; k0 < HH; k0 += 32) {
        const float4* ap = (const float4*)(hsrc + (long)sm * HH + k0 + skg * 8);
        float4 a0 = ap[0], a1 = ap[1];
        const float4* bp = (const float4*)(W_ho + (long)sn * HH + k0 + bkg * 8);
        float4 b0 = bp[0], b1 = bp[1];
        __syncthreads();
        bf16x8 av, bv;
        av[0] = f2bf(a0.x); av[1] = f2bf(a0.y); av[2] = f2bf(a0.z); av[3] = f2bf(a0.w);
        av[4] = f2bf(a1.x); av[5] = f2bf(a1.y); av[6] = f2bf(a1.z); av[7] = f2bf(a1.w);
        bv[0] = f2bf(b0.x); bv[1] = f2bf(b0.y); bv[2] = f2bf(b0.z); bv[3] = f2bf(b0.w);
        bv[4] = f2bf(b1.x); bv[5] = f2bf(b1.y); bv[6] = f2bf(b1.z); bv[7] = f2bf(b1.w);
        *(bf16x8*)&lA[sm * 40 + skg * 8] = av;
        *(bf16x8*)&lB[sn * 40 + bkg * 8] = bv;
        __syncthreads();
        bf16x8 af = *(const bf16x8*)&lA[(wave * 16 + l16) * 40 + quad * 8];
#pragma unroll
        for (int nt = 0; nt < 4; nt++) {
            bf16x8 bf = *(const bf16x8*)&lB[(nt * 16 + l16) * 40 + quad * 8];
            acc[nt] = __builtin_amdgcn_mfma_f32_16x16x32_bf16(af, bf, acc[nt], 0, 0, 0);
        }
    }
#pragma unroll
    for (int nt = 0; nt < 4; nt++) {
#pragma unroll
        for (int r = 0; r < 4; r++) {
            int mr = wave * 16 + quad * 4 + r;   // row within tile
            int col = nt * 16 + l16;
            xdst[(long)mr * DOUT + col] = acc[nt][r] + b_ho[col];
        }
    }
}

extern "C" void kernel_launch(void* const* d_in, const int* in_sizes, int n_in,
                              void* d_out, int out_size, void* d_ws, size_t ws_size,
                              hipStream_t stream) {
    const float* inp  = (const float*)d_in[0];
    const float* x0   = (const float*)d_in[1];
    const float* h0   = (const float*)d_in[2];
    const float* W_ih = (const float*)d_in[3];
    const float* b_ih = (const float*)d_in[4];
    const float* W_ho = (const float*)d_in[5];
    const float* b_ho = (const float*)d_in[6];
    float* out_x = (float*)d_out;
    float* out_h = out_x + X_ELEMS;

    // 1) U = b_ih + inputs @ W_u^T  -> h-rows 1..512 of d_out (scratch-in-place)
    gemm_u<<<dim3(2048, 4), 256, 0, stream>>>(inp, W_ih, b_ih, out_h);
    // 2) sequential recurrence, overwrites U rows with h trajectory
    rnn_seq<<<dim3(256), 512, 0, stream>>>(x0, h0, W_ih, out_x, out_h);
    // 3) x = h @ W_ho^T + b_ho for t=1..512
    gemm_x<<<dim3(2048), 256, 0, stream>>>(out_h, W_ho, b_ho, out_x);
}

// Round 2
// 516.151 us; speedup vs baseline: 1.0805x; 1.0805x over previous
//
#include <hip/hip_runtime.h>

// Problem constants
#define BB 256
#define TT 512
#define DIN 128
#define HH 256
#define DOUT 64
#define X_ELEMS ((long)BB * 513 * DOUT)

typedef short bf16x8 __attribute__((ext_vector_type(8)));
typedef float f32x4 __attribute__((ext_vector_type(4)));
typedef _Float16 half2_t __attribute__((ext_vector_type(2)));
typedef _Float16 half8_t __attribute__((ext_vector_type(8)));

static __device__ inline short f2bf(float f) {
    unsigned u = __float_as_uint(f);
    unsigned r = (u + 0x7FFFu + ((u >> 16) & 1u)) >> 16;
    return (short)r;
}

static __device__ inline float fdot2f(half2_t a, half2_t b, float c) {
#if __has_builtin(__builtin_amdgcn_fdot2)
    return __builtin_amdgcn_fdot2(a, b, c, false);
#else
    return c + (float)a[0] * (float)b[0] + (float)a[1] * (float)b[1];
#endif
}

// butterfly-add across a lane quad via DPP quad_perm (XOR1 then XOR2).
// All 4 lanes of the quad end up with the full 4-lane sum. Pure VALU.
static __device__ inline float quad_bfly_add(float x) {
    int t = __builtin_amdgcn_mov_dpp(__float_as_int(x), 0xB1, 0xF, 0xF, true); // [1,0,3,2]
    x += __int_as_float(t);
    t = __builtin_amdgcn_mov_dpp(__float_as_int(x), 0x4E, 0xF, 0xF, true);     // [2,3,0,1]
    x += __int_as_float(t);
    return x;
}

// ---------------------------------------------------------------------------
// Kernel A: U[b,t,:] = b_ih + inputs[b,t,:] @ W_u^T  (W_u = W_ih[:, 0:128])
// into h-rows 1..512 of d_out. Full-K staging, ONE barrier per block.
// grid (2048,4), block 256. Tile M64 x N64, K=128.
// ---------------------------------------------------------------------------
#define SA 136  // LDS row stride (shorts) for K=128: 272 B, 16-aligned
__global__ __launch_bounds__(256) void gemm_u(
        const float* __restrict__ inp, const float* __restrict__ W_ih,
        const float* __restrict__ b_ih, float* __restrict__ out_h) {
    __shared__ __align__(16) short lA[64 * SA];
    __shared__ __align__(16) short lB[64 * SA];
    const int tid = threadIdx.x;
    const int wave = tid >> 6, lane = tid & 63;
    const int quad = lane >> 4, l16 = lane & 15;
    const int m0 = blockIdx.x * 64;
    const int n0 = blockIdx.y * 64;
    const int sm = tid >> 2, skg = tid & 3;
    const int sn = tid & 63, bkg = tid >> 6;

    // issue ALL global loads up front, then convert+store to LDS, one barrier
    float4 a4[8], b4[8];
#pragma unroll
    for (int c = 0; c < 4; ++c) {
        const float4* ap = (const float4*)(inp + (long)(m0 + sm) * DIN + c * 32 + skg * 8);
        a4[2 * c] = ap[0]; a4[2 * c + 1] = ap[1];
        const float4* bp = (const float4*)(W_ih + (long)(n0 + sn) * 384 + c * 32 + bkg * 8);
        b4[2 * c] = bp[0]; b4[2 * c + 1] = bp[1];
    }
#pragma unroll
    for (int c = 0; c < 4; ++c) {
        bf16x8 av, bv;
        float4 x0 = a4[2 * c], x1 = a4[2 * c + 1];
        av[0] = f2bf(x0.x); av[1] = f2bf(x0.y); av[2] = f2bf(x0.z); av[3] = f2bf(x0.w);
        av[4] = f2bf(x1.x); av[5] = f2bf(x1.y); av[6] = f2bf(x1.z); av[7] = f2bf(x1.w);
        float4 y0 = b4[2 * c], y1 = b4[2 * c + 1];
        bv[0] = f2bf(y0.x); bv[1] = f2bf(y0.y); bv[2] = f2bf(y0.z); bv[3] = f2bf(y0.w);
        bv[4] = f2bf(y1.x); bv[5] = f2bf(y1.y); bv[6] = f2bf(y1.z); bv[7] = f2bf(y1.w);
        *(bf16x8*)&lA[sm * SA + c * 32 + skg * 8] = av;
        *(bf16x8*)&lB[sn * SA + c * 32 + bkg * 8] = bv;
    }
    __syncthreads();

    f32x4 acc[4];
#pragma unroll
    for (int i = 0; i < 4; i++) acc[i] = (f32x4){0.f, 0.f, 0.f, 0.f};
#pragma unroll
    for (int c = 0; c < 4; ++c) {
        bf16x8 af = *(const bf16x8*)&lA[(wave * 16 + l16) * SA + c * 32 + quad * 8];
#pragma unroll
        for (int nt = 0; nt < 4; ++nt) {
            bf16x8 bf = *(const bf16x8*)&lB[(nt * 16 + l16) * SA + c * 32 + quad * 8];
            acc[nt] = __builtin_amdgcn_mfma_f32_16x16x32_bf16(af, bf, acc[nt], 0, 0, 0);
        }
    }
#pragma unroll
    for (int nt = 0; nt < 4; ++nt) {
#pragma unroll
        for (int r = 0; r < 4; ++r) {
            int m = m0 + wave * 16 + quad * 4 + r;
            int col = n0 + nt * 16 + l16;
            long orow = (long)(m >> 9) * 513 + (m & 511) + 1;
            out_h[orow * HH + col] = acc[nt][r] + b_ih[col];
        }
    }
}

// ---------------------------------------------------------------------------
// Kernel B: sequential recurrence. grid 256 (1 block/batch), block 256 (4 waves).
// Thread (g = tid>>2, q = tid&3): outputs j = 4g..4g+3, k-quarter [64q, 64q+64).
// Weights 4x64 fp16 in regs (128 VGPRs). h fp16 in LDS, double-buffered,
// k-slices padded to 72 fp16 (disjoint bank groups per q). Per step:
// 8 ds_read_b128 + 128 v_dot2 + quad-DPP butterfly + 1 barrier.
// Reads U from out_h row t+1 (written by gemm_u), overwrites it with h.
// ---------------------------------------------------------------------------
__global__ __launch_bounds__(256) void rnn_seq(
        const float* __restrict__ x0, const float* __restrict__ h0,
        const float* __restrict__ W_ih,
        float* __restrict__ out_x, float* __restrict__ out_h) {
    __shared__ __align__(16) _Float16 hsh[2][4][72];
    const int b = blockIdx.x;
    const int tid = threadIdx.x;
    const int g = tid >> 2;        // j-group 0..63
    const int q = tid & 3;         // k-quarter
    const int jm = (g << 2) + q;   // this lane's own output index

    // weights W_h[4g+jp][64q + kk] -> w[jp][kk/2] as half2
    half2_t w[4][32];
    {
        const float* base = W_ih + 128 + 64 * q;
#pragma unroll
        for (int jp = 0; jp < 4; ++jp) {
            const float* wr = base + (long)(4 * g + jp) * 384;
#pragma unroll
            for (int i = 0; i < 16; ++i) {
                float4 v = *(const float4*)(wr + 4 * i);
                w[jp][2 * i]     = (half2_t){(_Float16)v.x, (_Float16)v.y};
                w[jp][2 * i + 1] = (half2_t){(_Float16)v.z, (_Float16)v.w};
            }
        }
    }

    float* hrow = out_h + (long)b * 513 * HH;
    // init: h0 -> LDS buf0 + global row 0; x0 -> x row 0; prefetch U row 1
    {
        float hv = h0[(long)b * HH + jm];
        hrow[jm] = hv;
        hsh[0][jm >> 6][jm & 63] = (_Float16)hv;
    }
    if (tid < DOUT) out_x[(long)b * 513 * DOUT + tid] = x0[(long)b * DOUT + tid];
    float u = hrow[HH + jm];
    __syncthreads();

    int cur = 0;
    for (int t = 0; t < TT; ++t) {
        const _Float16* hs = &hsh[cur][q][0];
        float a0 = 0.f, a1 = 0.f, a2 = 0.f, a3 = 0.f;
#pragma unroll
        for (int c = 0; c < 8; ++c) {
            half8_t hv = *(const half8_t*)(hs + 8 * c);
            half2_t p0 = {hv[0], hv[1]}, p1 = {hv[2], hv[3]};
            half2_t p2 = {hv[4], hv[5]}, p3 = {hv[6], hv[7]};
            a0 = fdot2f(p0, w[0][4 * c + 0], a0);
            a0 = fdot2f(p1, w[0][4 * c + 1], a0);
            a0 = fdot2f(p2, w[0][4 * c + 2], a0);
            a0 = fdot2f(p3, w[0][4 * c + 3], a0);
            a1 = fdot2f(p0, w[1][4 * c + 0], a1);
            a1 = fdot2f(p1, w[1][4 * c + 1], a1);
            a1 = fdot2f(p2, w[1][4 * c + 2], a1);
            a1 = fdot2f(p3, w[1][4 * c + 3], a1);
            a2 = fdot2f(p0, w[2][4 * c + 0], a2);
            a2 = fdot2f(p1, w[2][4 * c + 1], a2);
            a2 = fdot2f(p2, w[2][4 * c + 2], a2);
            a2 = fdot2f(p3, w[2][4 * c + 3], a2);
            a3 = fdot2f(p0, w[3][4 * c + 0], a3);
            a3 = fdot2f(p1, w[3][4 * c + 1], a3);
            a3 = fdot2f(p2, w[3][4 * c + 2], a3);
            a3 = fdot2f(p3, w[3][4 * c + 3], a3);
        }
        // quad butterfly: every lane gets full-k sums for all 4 j's of its group
        a0 = quad_bfly_add(a0);
        a1 = quad_bfly_add(a1);
        a2 = quad_bfly_add(a2);
        a3 = quad_bfly_add(a3);
        float s = (q == 0) ? a0 : (q == 1) ? a1 : (q == 2) ? a2 : a3;
        float tot = s + u;                            // u = U_t[jm] (has b_ih)
        float hn = tot >= 0.f ? tot : 0.01f * tot;    // LeakyReLU(0.01)
        int nxt = cur ^ 1;
        hsh[nxt][jm >> 6][jm & 63] = (_Float16)hn;    // contiguous b16 per wave
        hrow[(long)(t + 1) * HH + jm] = hn;           // coalesced dword store
        if (t < TT - 1) u = hrow[(long)(t + 2) * HH + jm];  // prefetch next U
        __syncthreads();
        cur = nxt;
    }
}

// ---------------------------------------------------------------------------
// Kernel C: x[b,t,:] = h[b,t,:] @ W_ho^T + b_ho, t=1..512.
// Full-K (256) staging, ONE barrier. grid 2048, block 256. Tile M64 x N64.
// ---------------------------------------------------------------------------
#define SX 264  // LDS row stride (shorts) for K=256: 528 B, 16-aligned
__global__ __launch_bounds__(256) void gemm_x(
        const float* __restrict__ out_h, const float* __restrict__ W_ho,
        const float* __restrict__ b_ho, float* __restrict__ out_x) {
    __shared__ __align__(16) short lA[64 * SX];
    __shared__ __align__(16) short lB[64 * SX];
    const int tid = threadIdx.x;
    const int wave = tid >> 6, lane = tid & 63;
    const int quad = lane >> 4, l16 = lane & 15;
    const int m0 = blockIdx.x * 64;
    const int bb = m0 >> 9, t0 = m0 & 511;
    const float* hsrc = out_h + ((long)bb * 513 + 1 + t0) * HH;
    float* xdst = out_x + ((long)bb * 513 + 1 + t0) * DOUT;
    const int sm = tid >> 2, skg = tid & 3;
    const int sn = tid & 63, bkg = tid >> 6;

#pragma unroll
    for (int ph = 0; ph < 2; ++ph) {   // two phases of 4 k-chunks to cap regs
        float4 a4[8], b4[8];
#pragma unroll
        for (int c = 0; c < 4; ++c) {
            int k0 = ph * 128 + c * 32;
            const float4* ap = (const float4*)(hsrc + (long)sm * HH + k0 + skg * 8);
            a4[2 * c] = ap[0]; a4[2 * c + 1] = ap[1];
            const float4* bp = (const float4*)(W_ho + (long)sn * HH + k0 + bkg * 8);
            b4[2 * c] = bp[0]; b4[2 * c + 1] = bp[1];
        }
#pragma unroll
        for (int c = 0; c < 4; ++c) {
            int k0 = ph * 128 + c * 32;
            bf16x8 av, bv;
            float4 x0 = a4[2 * c], x1 = a4[2 * c + 1];
            av[0] = f2bf(x0.x); av[1] = f2bf(x0.y); av[2] = f2bf(x0.z); av[3] = f2bf(x0.w);
            av[4] = f2bf(x1.x); av[5] = f2bf(x1.y); av[6] = f2bf(x1.z); av[7] = f2bf(x1.w);
            float4 y0 = b4[2 * c], y1 = b4[2 * c + 1];
            bv[0] = f2bf(y0.x); bv[1] = f2bf(y0.y); bv[2] = f2bf(y0.z); bv[3] = f2bf(y0.w);
            bv[4] = f2bf(y1.x); bv[5] = f2bf(y1.y); bv[6] = f2bf(y1.z); bv[7] = f2bf(y1.w);
            *(bf16x8*)&lA[sm * SX + k0 + skg * 8] = av;
            *(bf16x8*)&lB[sn * SX + k0 + bkg * 8] = bv;
        }
    }
    __syncthreads();

    f32x4 acc[4];
#pragma unroll
    for (int i = 0; i < 4; i++) acc[i] = (f32x4){0.f, 0.f, 0.f, 0.f};
#pragma unroll
    for (int c = 0; c < 8; ++c) {
        bf16x8 af = *(const bf16x8*)&lA[(wave * 16 + l16) * SX + c * 32 + quad * 8];
#pragma unroll
        for (int nt = 0; nt < 4; ++nt) {
            bf16x8 bf = *(const bf16x8*)&lB[(nt * 16 + l16) * SX + c * 32 + quad * 8];
            acc[nt] = __builtin_amdgcn_mfma_f32_16x16x32_bf16(af, bf, acc[nt], 0, 0, 0);
        }
    }
#pragma unroll
    for (int nt = 0; nt < 4; ++nt) {
#pragma unroll
        for (int r = 0; r < 4; ++r) {
            int mr = wave * 16 + quad * 4 + r;
            int col = nt * 16 + l16;
            xdst[(long)mr * DOUT + col] = acc[nt][r] + b_ho[col];
        }
    }
}

extern "C" void kernel_launch(void* const* d_in, const int* in_sizes, int n_in,
                              void* d_out, int out_size, void* d_ws, size_t ws_size,
                              hipStream_t stream) {
    const float* inp  = (const float*)d_in[0];
    const float* x0   = (const float*)d_in[1];
    const float* h0   = (const float*)d_in[2];
    const float* W_ih = (const float*)d_in[3];
    const float* b_ih = (const float*)d_in[4];
    const float* W_ho = (const float*)d_in[5];
    const float* b_ho = (const float*)d_in[6];
    float* out_x = (float*)d_out;
    float* out_h = out_x + X_ELEMS;

    gemm_u<<<dim3(2048, 4), 256, 0, stream>>>(inp, W_ih, b_ih, out_h);
    rnn_seq<<<dim3(256), 256, 0, stream>>>(x0, h0, W_ih, out_x, out_h);
    gemm_x<<<dim3(2048), 256, 0, stream>>>(out_h, W_ho, b_ho, out_x);
}